// Round 2
// baseline (405.718 us; speedup 1.0000x reference)
//
#include <hip/hip_runtime.h>
#include <hip/hip_bf16.h>

typedef __attribute__((ext_vector_type(8))) __bf16 bf8_t;
typedef __attribute__((ext_vector_type(4))) float f32x4;

__device__ __forceinline__ unsigned short f2bf(float f) {
  union { float f; unsigned u; } v; v.f = f;
  return (unsigned short)((v.u + 0x7fffu + ((v.u >> 16) & 1u)) >> 16);
}

// ---------- cast f32 -> bf16, same layout, 4 elems/thread ----------
__global__ void cast_bf16(const float* __restrict__ in, unsigned short* __restrict__ out, int n4) {
  int i = blockIdx.x * blockDim.x + threadIdx.x;
  if (i >= n4) return;
  float4 v = ((const float4*)in)[i];
  ushort4 o;
  o.x = f2bf(v.x); o.y = f2bf(v.y); o.z = f2bf(v.z); o.w = f2bf(v.w);
  ((ushort4*)out)[i] = o;
}

// ---------- transpose-cast: in[R][C] f32 -> out[(rowOff+c)*ld + r] bf16 ----------
__global__ void tcast(const float* __restrict__ in, unsigned short* __restrict__ out,
                      int R, int C, int ld, int rowOff) {
  __shared__ float tile[32][33];
  int c0 = blockIdx.x * 32, r0 = blockIdx.y * 32;
  int tx = threadIdx.x, ty = threadIdx.y;
#pragma unroll
  for (int i = 0; i < 4; ++i)
    tile[ty + 8 * i][tx] = in[(size_t)(r0 + ty + 8 * i) * C + c0 + tx];
  __syncthreads();
#pragma unroll
  for (int i = 0; i < 4; ++i)
    out[(size_t)(rowOff + c0 + ty + 8 * i) * ld + r0 + tx] = f2bf(tile[tx][ty + 8 * i]);
}

// ---------- bf16 MFMA GEMM: C[M][N] f32 = A[M][K] * Bt[N][K]^T ----------
__global__ __launch_bounds__(256) void gemm_bt(
    const unsigned short* __restrict__ A,
    const unsigned short* __restrict__ Bt,
    float* __restrict__ C, int M, int N, int K) {
  __shared__ short As[128][72];
  __shared__ short Bs[128][72];
  int nblk = N >> 7;
  int bm = blockIdx.x / nblk, bn = blockIdx.x % nblk;
  int m0 = bm << 7, n0 = bn << 7;
  int tid = threadIdx.x, lane = tid & 63, w = tid >> 6;
  int wm = (w >> 1) << 6, wn = (w & 1) << 6;
  int lrow = lane & 15, lko = (lane >> 4) << 3;
  f32x4 acc[4][4] = {};
  for (int k0 = 0; k0 < K; k0 += 64) {
#pragma unroll
    for (int c = 0; c < 4; ++c) {
      int e = (c * 256 + tid) * 8;
      int row = e >> 6, col = e & 63;
      *(int4*)(&As[row][col]) = *(const int4*)(A + (size_t)(m0 + row) * K + k0 + col);
      *(int4*)(&Bs[row][col]) = *(const int4*)(Bt + (size_t)(n0 + row) * K + k0 + col);
    }
    __syncthreads();
#pragma unroll
    for (int ks = 0; ks < 2; ++ks) {
      bf8_t a[4], b[4];
#pragma unroll
      for (int mi = 0; mi < 4; ++mi) a[mi] = *(const bf8_t*)(&As[wm + mi * 16 + lrow][ks * 32 + lko]);
#pragma unroll
      for (int ni = 0; ni < 4; ++ni) b[ni] = *(const bf8_t*)(&Bs[wn + ni * 16 + lrow][ks * 32 + lko]);
#pragma unroll
      for (int mi = 0; mi < 4; ++mi)
#pragma unroll
        for (int ni = 0; ni < 4; ++ni)
          acc[mi][ni] = __builtin_amdgcn_mfma_f32_16x16x32_bf16(a[mi], b[ni], acc[mi][ni], 0, 0, 0);
    }
    __syncthreads();
  }
  int r0c = m0 + wm + ((lane >> 4) << 2);
  int c0c = n0 + wn + lrow;
#pragma unroll
  for (int mi = 0; mi < 4; ++mi)
#pragma unroll
    for (int ni = 0; ni < 4; ++ni)
#pragma unroll
      for (int r = 0; r < 4; ++r)
        C[(size_t)(r0c + mi * 16 + r) * N + c0c + ni * 16] = acc[mi][ni][r];
}

// ---------- fused RMS-norm + RoPE + layout shuffle ----------
// qkv f32 [2048][6144]; writes q_bf [B][32][T][128], k_bf [B][8][T][128],
// vt_bf [B][8][128][1024] (V pre-transposed for attention staging).
__global__ __launch_bounds__(128) void normrope(
    const float* __restrict__ qkv, const int* __restrict__ positions,
    const float* __restrict__ qw, const float* __restrict__ kw,
    unsigned short* __restrict__ qb, unsigned short* __restrict__ kb,
    unsigned short* __restrict__ vt) {
  int blk = blockIdx.x;
  int hh = blk % 48, bt = blk / 48;
  int b = bt >> 10, t = bt & 1023;
  int tid = threadIdx.x;
  int colbase = (hh < 32) ? (hh << 7) : ((hh < 40) ? (4096 + ((hh - 32) << 7)) : (5120 + ((hh - 40) << 7)));
  float val = qkv[(size_t)bt * 6144 + colbase + tid];
  if (hh >= 40) {  // V: no norm/rope, write transposed [dim][seq]
    vt[((size_t)((b * 8 + hh - 40) * 128 + tid)) * 1024 + t] = f2bf(val);
    return;
  }
  __shared__ float red[2];
  __shared__ float xs[128];
  float ss = val * val;
#pragma unroll
  for (int m = 32; m >= 1; m >>= 1) ss += __shfl_xor(ss, m);
  if ((tid & 63) == 0) red[tid >> 6] = ss;
  __syncthreads();
  float rinv = rsqrtf((red[0] + red[1]) * (1.0f / 128.0f) + 1e-6f);
  float wgt = (hh < 32) ? qw[tid] : kw[tid];
  float xn = val * rinv * wgt;
  xs[tid] = xn;
  __syncthreads();
  float other = xs[tid ^ 64];
  int pos = positions[b * 1024 + t];  // section 0 (all 3 identical: arange)
  int j = tid & 63;
  float ang = (float)pos * exp2f(-(float)j * 0.31143075889569027f);  // log2(1e6)/64
  float sv = sinf(ang), cv = cosf(ang);
  float outv = (tid < 64) ? (xn * cv - other * sv) : (xn * cv + other * sv);
  unsigned short o = f2bf(outv);
  if (hh < 32) qb[((size_t)((b * 32 + hh) * 1024 + t)) * 128 + tid] = o;
  else kb[((size_t)((b * 8 + hh - 32) * 1024 + t)) * 128 + tid] = o;
}

// ---------- flash attention, causal, GQA 32q/8kv ----------
__global__ __launch_bounds__(256) void attn(
    const unsigned short* __restrict__ qb,
    const unsigned short* __restrict__ kb,
    const unsigned short* __restrict__ vt,
    unsigned short* __restrict__ ob) {
  __shared__ short Ks[64][136];
  __shared__ short Vs[128][72];   // V^T tile: [dim][s]
  __shared__ short Ps[4][16][72]; // per-wave P buffer
  int qt = blockIdx.x, hq = blockIdx.y, b = blockIdx.z;
  int kvh = hq >> 2;
  int tid = threadIdx.x, lane = tid & 63, w = tid >> 6;
  int lrow = lane & 15, lko = (lane >> 4) << 3;
  int qbase = qt << 6;
  const unsigned short* qp = qb + ((size_t)((b * 32 + hq) * 1024 + qbase + w * 16 + lrow)) * 128;
  bf8_t qa[4];
#pragma unroll
  for (int kk = 0; kk < 4; ++kk) qa[kk] = *(const bf8_t*)(qp + kk * 32 + lko);
  f32x4 accO[8] = {};
  float mrun[4], lrun[4];
#pragma unroll
  for (int r = 0; r < 4; ++r) { mrun[r] = -3.0e38f; lrun[r] = 0.f; }
  const unsigned short* kbase = kb + ((size_t)(b * 8 + kvh) * 1024) * 128;
  const unsigned short* vbase = vt + ((size_t)(b * 8 + kvh) * 128) * 1024;
  const float scale = 0.08838834764831845f;

  for (int st = 0; st <= qt; ++st) {
    int s0 = st << 6;
#pragma unroll
    for (int c = 0; c < 4; ++c) {
      int e = (c * 256 + tid) * 8;
      int krow = e >> 7, kcol = e & 127;  // K tile 64x128
      *(int4*)(&Ks[krow][kcol]) = *(const int4*)(kbase + (size_t)(s0 + krow) * 128 + kcol);
      int vrow = e >> 6, vcol = e & 63;   // Vt tile 128x64
      *(int4*)(&Vs[vrow][vcol]) = *(const int4*)(vbase + (size_t)vrow * 1024 + s0 + vcol);
    }
    __syncthreads();
    f32x4 sacc[4] = {};
#pragma unroll
    for (int kk = 0; kk < 4; ++kk) {
      bf8_t qf = qa[kk];
#pragma unroll
      for (int ni = 0; ni < 4; ++ni) {
        bf8_t kf = *(const bf8_t*)(&Ks[ni * 16 + lrow][kk * 32 + lko]);
        sacc[ni] = __builtin_amdgcn_mfma_f32_16x16x32_bf16(qf, kf, sacc[ni], 0, 0, 0);
      }
    }
    float p[4][4];
    float rmax[4];
#pragma unroll
    for (int r = 0; r < 4; ++r) rmax[r] = -3.0e38f;
    int qrow0 = qbase + w * 16 + ((lane >> 4) << 2);
#pragma unroll
    for (int ni = 0; ni < 4; ++ni) {
      int sc = s0 + ni * 16 + lrow;
#pragma unroll
      for (int r = 0; r < 4; ++r) {
        float sv = sacc[ni][r] * scale;
        sv = (sc <= qrow0 + r) ? sv : -3.0e38f;
        p[ni][r] = sv;
        rmax[r] = fmaxf(rmax[r], sv);
      }
    }
#pragma unroll
    for (int m = 1; m <= 8; m <<= 1)
#pragma unroll
      for (int r = 0; r < 4; ++r) rmax[r] = fmaxf(rmax[r], __shfl_xor(rmax[r], m));
    float alpha[4], rsum[4];
#pragma unroll
    for (int r = 0; r < 4; ++r) {
      float mn = fmaxf(mrun[r], rmax[r]);
      alpha[r] = __expf(mrun[r] - mn);
      mrun[r] = mn;
      rsum[r] = 0.f;
    }
#pragma unroll
    for (int ni = 0; ni < 4; ++ni)
#pragma unroll
      for (int r = 0; r < 4; ++r) {
        float e = __expf(p[ni][r] - mrun[r]);
        p[ni][r] = e;
        rsum[r] += e;
      }
#pragma unroll
    for (int m = 1; m <= 8; m <<= 1)
#pragma unroll
      for (int r = 0; r < 4; ++r) rsum[r] += __shfl_xor(rsum[r], m);
#pragma unroll
    for (int r = 0; r < 4; ++r) lrun[r] = lrun[r] * alpha[r] + rsum[r];
#pragma unroll
    for (int ni = 0; ni < 8; ++ni)
#pragma unroll
      for (int r = 0; r < 4; ++r) accO[ni][r] *= alpha[r];
    // P: D-layout -> A-layout via wave-private LDS
#pragma unroll
    for (int ni = 0; ni < 4; ++ni)
#pragma unroll
      for (int r = 0; r < 4; ++r)
        Ps[w][((lane >> 4) << 2) + r][ni * 16 + lrow] = (short)f2bf(p[ni][r]);
    bf8_t pa0 = *(const bf8_t*)(&Ps[w][lrow][lko]);
    bf8_t pa1 = *(const bf8_t*)(&Ps[w][lrow][32 + lko]);
#pragma unroll
    for (int ni = 0; ni < 8; ++ni) {
      bf8_t v0 = *(const bf8_t*)(&Vs[ni * 16 + lrow][lko]);
      bf8_t v1 = *(const bf8_t*)(&Vs[ni * 16 + lrow][32 + lko]);
      accO[ni] = __builtin_amdgcn_mfma_f32_16x16x32_bf16(pa0, v0, accO[ni], 0, 0, 0);
      accO[ni] = __builtin_amdgcn_mfma_f32_16x16x32_bf16(pa1, v1, accO[ni], 0, 0, 0);
    }
    __syncthreads();
  }
  size_t row0 = (size_t)(b * 1024) + qbase + w * 16 + ((lane >> 4) << 2);
#pragma unroll
  for (int r = 0; r < 4; ++r) {
    float inv = 1.0f / lrun[r];
#pragma unroll
    for (int ni = 0; ni < 8; ++ni)
      ob[(row0 + r) * 4096 + hq * 128 + ni * 16 + lrow] = f2bf(accO[ni][r] * inv);
  }
}

extern "C" void kernel_launch(void* const* d_in, const int* in_sizes, int n_in,
                              void* d_out, int out_size, void* d_ws, size_t ws_size,
                              hipStream_t stream) {
  const float* x = (const float*)d_in[0];
  const int* positions = (const int*)d_in[1];
  // d_in[2] = attn_mask (guaranteed causal tril by setup; computed analytically)
  const float* wq = (const float*)d_in[3];
  const float* wk = (const float*)d_in[4];
  const float* wv = (const float*)d_in[5];
  const float* wo = (const float*)d_in[6];
  const float* qnw = (const float*)d_in[7];
  const float* knw = (const float*)d_in[8];
  float* out = (float*)d_out;

  char* ws = (char*)d_ws;
  unsigned short* x_bf  = (unsigned short*)(ws);              // 2048x2560
  unsigned short* wqkvT = (unsigned short*)(ws + 10485760);   // 6144x2560
  unsigned short* woT   = (unsigned short*)(ws + 41943040);   // 2560x4096
  float*          qkv   = (float*)(ws + 62914560);            // 2048x6144 f32
  unsigned short* q_bf  = (unsigned short*)(ws + 113246208);  // [2][32][1024][128]
  unsigned short* k_bf  = (unsigned short*)(ws + 130023424);  // [2][8][1024][128]
  unsigned short* vt_bf = (unsigned short*)(ws + 134217728);  // [2][8][128][1024]
  unsigned short* a_bf  = (unsigned short*)(ws + 138412032);  // 2048x4096

  cast_bf16<<<5120, 256, 0, stream>>>(x, x_bf, 2048 * 2560 / 4);
  tcast<<<dim3(128, 80), dim3(32, 8), 0, stream>>>(wq, wqkvT, 2560, 4096, 2560, 0);
  tcast<<<dim3(32, 80), dim3(32, 8), 0, stream>>>(wk, wqkvT, 2560, 1024, 2560, 4096);
  tcast<<<dim3(32, 80), dim3(32, 8), 0, stream>>>(wv, wqkvT, 2560, 1024, 2560, 5120);
  tcast<<<dim3(80, 128), dim3(32, 8), 0, stream>>>(wo, woT, 4096, 2560, 4096, 0);
  gemm_bt<<<16 * 48, 256, 0, stream>>>(x_bf, wqkvT, qkv, 2048, 6144, 2560);
  normrope<<<2048 * 48, 128, 0, stream>>>(qkv, positions, qnw, knw, q_bf, k_bf, vt_bf);
  attn<<<dim3(16, 32, 2), 256, 0, stream>>>(q_bf, k_bf, vt_bf, a_bf);
  gemm_bt<<<16 * 20, 256, 0, stream>>>(a_bf, woT, out, 2048, 2560, 4096);
}

// Round 3
// 380.793 us; speedup vs baseline: 1.0655x; 1.0655x over previous
//
#include <hip/hip_runtime.h>
#include <hip/hip_bf16.h>

typedef __attribute__((ext_vector_type(8))) __bf16 bf8_t;
typedef __attribute__((ext_vector_type(4))) float f32x4;

#define GLOAD16(gptr, lptr)                                                              \
  __builtin_amdgcn_global_load_lds((const __attribute__((address_space(1))) void*)(gptr), \
                                   (__attribute__((address_space(3))) void*)(lptr), 16, 0, 0)

__device__ __forceinline__ unsigned short f2bf(float f) {
  union { float f; unsigned u; } v; v.f = f;
  return (unsigned short)((v.u + 0x7fffu + ((v.u >> 16) & 1u)) >> 16);
}

// ---------- cast f32 -> bf16 ----------
__global__ void cast_bf16(const float* __restrict__ in, unsigned short* __restrict__ out, int n4) {
  int i = blockIdx.x * blockDim.x + threadIdx.x;
  if (i >= n4) return;
  float4 v = ((const float4*)in)[i];
  ushort4 o;
  o.x = f2bf(v.x); o.y = f2bf(v.y); o.z = f2bf(v.z); o.w = f2bf(v.w);
  ((ushort4*)out)[i] = o;
}

// ---------- transpose-cast ----------
__global__ void tcast(const float* __restrict__ in, unsigned short* __restrict__ out,
                      int R, int C, int ld, int rowOff) {
  __shared__ float tile[32][33];
  int c0 = blockIdx.x * 32, r0 = blockIdx.y * 32;
  int tx = threadIdx.x, ty = threadIdx.y;
#pragma unroll
  for (int i = 0; i < 4; ++i)
    tile[ty + 8 * i][tx] = in[(size_t)(r0 + ty + 8 * i) * C + c0 + tx];
  __syncthreads();
#pragma unroll
  for (int i = 0; i < 4; ++i)
    out[(size_t)(rowOff + c0 + ty + 8 * i) * ld + r0 + tx] = f2bf(tile[tx][ty + 8 * i]);
}

// ---------- bf16 MFMA GEMM (m97 structure: linear LDS + global_load_lds x4) ----------
__global__ __launch_bounds__(256) void gemm_bt(
    const unsigned short* __restrict__ A,
    const unsigned short* __restrict__ Bt,
    float* __restrict__ C, int M, int N, int K) {
  __shared__ unsigned short As[128 * 64];
  __shared__ unsigned short Bs[128 * 64];
  int nblk = N >> 7;
  int bm = blockIdx.x / nblk, bn = blockIdx.x % nblk;
  int m0 = bm << 7, n0 = bn << 7;
  int tid = threadIdx.x, lane = tid & 63, w = tid >> 6;
  int wm = (w >> 1) << 6, wn = (w & 1) << 6;
  int lrow = lane & 15, lko = (lane >> 4) << 3;
  int srow = lane >> 3, scol = (lane & 7) << 3;  // staging: 8 rows/stripe, 8 chunks/row
  f32x4 acc[4][4] = {};
  for (int k0 = 0; k0 < K; k0 += 64) {
#pragma unroll
    for (int i = 0; i < 4; ++i) {
      int si = (w << 2) + i;
      int r = (si << 3) + srow;
      GLOAD16(A + (size_t)(m0 + r) * K + k0 + scol, &As[(si << 3) * 64]);
      GLOAD16(Bt + (size_t)(n0 + r) * K + k0 + scol, &Bs[(si << 3) * 64]);
    }
    __syncthreads();
#pragma unroll
    for (int ks = 0; ks < 2; ++ks) {
      bf8_t a[4], b[4];
#pragma unroll
      for (int mi = 0; mi < 4; ++mi) a[mi] = *(const bf8_t*)(&As[(wm + mi * 16 + lrow) * 64 + ks * 32 + lko]);
#pragma unroll
      for (int ni = 0; ni < 4; ++ni) b[ni] = *(const bf8_t*)(&Bs[(wn + ni * 16 + lrow) * 64 + ks * 32 + lko]);
#pragma unroll
      for (int mi = 0; mi < 4; ++mi)
#pragma unroll
        for (int ni = 0; ni < 4; ++ni)
          acc[mi][ni] = __builtin_amdgcn_mfma_f32_16x16x32_bf16(a[mi], b[ni], acc[mi][ni], 0, 0, 0);
    }
    __syncthreads();
  }
  int r0c = m0 + wm + ((lane >> 4) << 2);
  int c0c = n0 + wn + lrow;
#pragma unroll
  for (int mi = 0; mi < 4; ++mi)
#pragma unroll
    for (int ni = 0; ni < 4; ++ni)
#pragma unroll
      for (int r = 0; r < 4; ++r)
        C[(size_t)(r0c + mi * 16 + r) * N + c0c + ni * 16] = acc[mi][ni][r];
}

// ---------- fused RMS-norm + RoPE + layout shuffle ----------
__global__ __launch_bounds__(128) void normrope(
    const float* __restrict__ qkv, const int* __restrict__ positions,
    const float* __restrict__ qw, const float* __restrict__ kw,
    unsigned short* __restrict__ qb, unsigned short* __restrict__ kb,
    unsigned short* __restrict__ vt) {
  int blk = blockIdx.x;
  int hh = blk % 48, bt = blk / 48;
  int b = bt >> 10, t = bt & 1023;
  int tid = threadIdx.x;
  int colbase = (hh < 32) ? (hh << 7) : ((hh < 40) ? (4096 + ((hh - 32) << 7)) : (5120 + ((hh - 40) << 7)));
  float val = qkv[(size_t)bt * 6144 + colbase + tid];
  if (hh >= 40) {
    vt[((size_t)((b * 8 + hh - 40) * 128 + tid)) * 1024 + t] = f2bf(val);
    return;
  }
  __shared__ float red[2];
  __shared__ float xs[128];
  float ss = val * val;
#pragma unroll
  for (int m = 32; m >= 1; m >>= 1) ss += __shfl_xor(ss, m);
  if ((tid & 63) == 0) red[tid >> 6] = ss;
  __syncthreads();
  float rinv = rsqrtf((red[0] + red[1]) * (1.0f / 128.0f) + 1e-6f);
  float wgt = (hh < 32) ? qw[tid] : kw[tid];
  float xn = val * rinv * wgt;
  xs[tid] = xn;
  __syncthreads();
  float other = xs[tid ^ 64];
  int pos = positions[b * 1024 + t];
  int j = tid & 63;
  float ang = (float)pos * exp2f(-(float)j * 0.31143075889569027f);
  float sv = sinf(ang), cv = cosf(ang);
  float outv = (tid < 64) ? (xn * cv - other * sv) : (xn * cv + other * sv);
  unsigned short o = f2bf(outv);
  if (hh < 32) qb[((size_t)((b * 32 + hh) * 1024 + t)) * 128 + tid] = o;
  else kb[((size_t)((b * 8 + hh - 32) * 1024 + t)) * 128 + tid] = o;
}

// ---------- flash attention v2: paired Q-tiles, dbuf gload staging, swizzled LDS ----------
__global__ __launch_bounds__(256) void attn(
    const unsigned short* __restrict__ qb,
    const unsigned short* __restrict__ kb,
    const unsigned short* __restrict__ vt,
    unsigned short* __restrict__ ob) {
  __shared__ unsigned short Ks[2][64 * 128];   // [buf] row-major 64x128, 16B-chunk XOR swizzle
  __shared__ unsigned short Vs[2][128 * 64];   // [buf] V^T 128x64, swizzled
  __shared__ unsigned short Ps[4][16 * 72];    // per-wave P relayout buffer
  int qpair = blockIdx.x, hq = blockIdx.y, b = blockIdx.z;
  int qtA = qpair, qtB = 15 - qpair;
  int kvh = hq >> 2;
  int tid = threadIdx.x, lane = tid & 63, w = tid >> 6;
  int lrow = lane & 15, lko = (lane >> 4) << 3;
  const float scale = 0.08838834764831845f;

  const unsigned short* kbase = kb + ((size_t)(b * 8 + kvh) << 17);
  const unsigned short* vbase = vt + ((size_t)(b * 8 + kvh) << 17);

  int qArow = (qtA << 6) + (w << 4) + lrow;
  int qBrow = (qtB << 6) + (w << 4) + lrow;
  const unsigned short* qpA = qb + ((size_t)((b * 32 + hq) * 1024 + qArow) << 7);
  const unsigned short* qpB = qb + ((size_t)((b * 32 + hq) * 1024 + qBrow) << 7);
  bf8_t qaA[4], qaB[4];
#pragma unroll
  for (int kk = 0; kk < 4; ++kk) {
    qaA[kk] = *(const bf8_t*)(qpA + kk * 32 + lko);
    qaB[kk] = *(const bf8_t*)(qpB + kk * 32 + lko);
  }
  f32x4 accA[8] = {}, accB[8] = {};
  float mA[4], lA[4], mB[4], lB[4];
#pragma unroll
  for (int r = 0; r < 4; ++r) { mA[r] = mB[r] = -3.0e38f; lA[r] = lB[r] = 0.f; }

  int kr_l = lane >> 4, kc_l = lane & 15;  // K staging: 4 rows/stripe, 16 chunks/row
  int vr_l = lane >> 3, vc_l = lane & 7;   // V staging: 8 rows/stripe, 8 chunks/row

  auto stage = [&](int st, int buf) {
    int s0 = st << 6;
    unsigned short* kd = &Ks[buf][0];
    unsigned short* vd = &Vs[buf][0];
#pragma unroll
    for (int i = 0; i < 4; ++i) {
      int si = (w << 2) + i;
      int kr = (si << 2) + kr_l;
      GLOAD16(kbase + (size_t)(s0 + kr) * 128 + ((kc_l ^ (kr & 7)) << 3), kd + (si << 9));
      int vr = (si << 3) + vr_l;
      GLOAD16(vbase + (size_t)vr * 1024 + s0 + ((vc_l ^ (vr & 7)) << 3), vd + (si << 9));
    }
  };

  int qArow0 = (qtA << 6) + (w << 4) + ((lane >> 4) << 2);
  int qBrow0 = (qtB << 6) + (w << 4) + ((lane >> 4) << 2);
  unsigned short* psw = &Ps[w][0];

  auto tilec = [&](int buf, int s0, const bf8_t* qa, f32x4* accO, float* mrun, float* lrun,
                   int qrow0, bool domask) {
    const char* Kb = (const char*)&Ks[buf][0];
    const char* Vb = (const char*)&Vs[buf][0];
    f32x4 sacc[4] = {};
#pragma unroll
    for (int kk = 0; kk < 4; ++kk)
#pragma unroll
      for (int ni = 0; ni < 4; ++ni) {
        int kr = (ni << 4) + lrow;
        const bf8_t* kf = (const bf8_t*)(Kb + kr * 256 + ((((kk << 2) | (lko >> 3)) ^ (kr & 7)) << 4));
        sacc[ni] = __builtin_amdgcn_mfma_f32_16x16x32_bf16(qa[kk], *kf, sacc[ni], 0, 0, 0);
      }
    float p[4][4], rmax[4];
#pragma unroll
    for (int r = 0; r < 4; ++r) rmax[r] = -3.0e38f;
#pragma unroll
    for (int ni = 0; ni < 4; ++ni) {
      int sc = s0 + ni * 16 + lrow;
#pragma unroll
      for (int r = 0; r < 4; ++r) {
        float sv = sacc[ni][r] * scale;
        if (domask) sv = (sc <= qrow0 + r) ? sv : -3.0e38f;
        p[ni][r] = sv;
        rmax[r] = fmaxf(rmax[r], sv);
      }
    }
#pragma unroll
    for (int m = 1; m <= 8; m <<= 1)
#pragma unroll
      for (int r = 0; r < 4; ++r) rmax[r] = fmaxf(rmax[r], __shfl_xor(rmax[r], m));
    float alpha[4], rsum[4];
#pragma unroll
    for (int r = 0; r < 4; ++r) {
      float mn = fmaxf(mrun[r], rmax[r]);
      alpha[r] = __expf(mrun[r] - mn);
      mrun[r] = mn;
      rsum[r] = 0.f;
    }
#pragma unroll
    for (int ni = 0; ni < 4; ++ni)
#pragma unroll
      for (int r = 0; r < 4; ++r) {
        float e = __expf(p[ni][r] - mrun[r]);
        p[ni][r] = e;
        rsum[r] += e;
      }
#pragma unroll
    for (int m = 1; m <= 8; m <<= 1)
#pragma unroll
      for (int r = 0; r < 4; ++r) rsum[r] += __shfl_xor(rsum[r], m);
#pragma unroll
    for (int r = 0; r < 4; ++r) lrun[r] = lrun[r] * alpha[r] + rsum[r];
#pragma unroll
    for (int ni = 0; ni < 8; ++ni)
#pragma unroll
      for (int r = 0; r < 4; ++r) accO[ni][r] *= alpha[r];
#pragma unroll
    for (int ni = 0; ni < 4; ++ni)
#pragma unroll
      for (int r = 0; r < 4; ++r)
        psw[(((lane >> 4) << 2) + r) * 72 + ni * 16 + lrow] = f2bf(p[ni][r]);
    bf8_t pa0 = *(const bf8_t*)(psw + lrow * 72 + lko);
    bf8_t pa1 = *(const bf8_t*)(psw + lrow * 72 + 32 + lko);
#pragma unroll
    for (int ni = 0; ni < 8; ++ni) {
      int vr = (ni << 4) + lrow;
      const bf8_t* v0 = (const bf8_t*)(Vb + vr * 128 + (((lko >> 3) ^ (vr & 7)) << 4));
      const bf8_t* v1 = (const bf8_t*)(Vb + vr * 128 + (((4 | (lko >> 3)) ^ (vr & 7)) << 4));
      accO[ni] = __builtin_amdgcn_mfma_f32_16x16x32_bf16(pa0, *v0, accO[ni], 0, 0, 0);
      accO[ni] = __builtin_amdgcn_mfma_f32_16x16x32_bf16(pa1, *v1, accO[ni], 0, 0, 0);
    }
  };

  stage(0, 0);
  for (int st = 0; st <= qtB; ++st) {
    int buf = st & 1;
    __syncthreads();  // drains vmcnt: staged tile ready; prior LDS reads done
    if (st < qtB) stage(st + 1, buf ^ 1);
    if (st <= qtA) tilec(buf, st << 6, qaA, accA, mA, lA, qArow0, st == qtA);
    tilec(buf, st << 6, qaB, accB, mB, lB, qBrow0, st == qtB);
  }

  size_t rowA = (size_t)(b * 1024) + (qtA << 6) + (w << 4) + ((lane >> 4) << 2);
  size_t rowB = (size_t)(b * 1024) + (qtB << 6) + (w << 4) + ((lane >> 4) << 2);
#pragma unroll
  for (int r = 0; r < 4; ++r) {
    float invA = 1.0f / lA[r], invB = 1.0f / lB[r];
#pragma unroll
    for (int ni = 0; ni < 8; ++ni) {
      ob[(rowA + r) * 4096 + hq * 128 + ni * 16 + lrow] = f2bf(accA[ni][r] * invA);
      ob[(rowB + r) * 4096 + hq * 128 + ni * 16 + lrow] = f2bf(accB[ni][r] * invB);
    }
  }
}

extern "C" void kernel_launch(void* const* d_in, const int* in_sizes, int n_in,
                              void* d_out, int out_size, void* d_ws, size_t ws_size,
                              hipStream_t stream) {
  const float* x = (const float*)d_in[0];
  const int* positions = (const int*)d_in[1];
  const float* wq = (const float*)d_in[3];
  const float* wk = (const float*)d_in[4];
  const float* wv = (const float*)d_in[5];
  const float* wo = (const float*)d_in[6];
  const float* qnw = (const float*)d_in[7];
  const float* knw = (const float*)d_in[8];
  float* out = (float*)d_out;

  char* ws = (char*)d_ws;
  unsigned short* x_bf  = (unsigned short*)(ws);              // 2048x2560
  unsigned short* wqkvT = (unsigned short*)(ws + 10485760);   // 6144x2560
  unsigned short* woT   = (unsigned short*)(ws + 41943040);   // 2560x4096
  float*          qkv   = (float*)(ws + 62914560);            // 2048x6144 f32
  unsigned short* q_bf  = (unsigned short*)(ws + 113246208);  // [2][32][1024][128]
  unsigned short* k_bf  = (unsigned short*)(ws + 130023424);  // [2][8][1024][128]
  unsigned short* vt_bf = (unsigned short*)(ws + 134217728);  // [2][8][128][1024]
  unsigned short* a_bf  = (unsigned short*)(ws + 138412032);  // 2048x4096

  cast_bf16<<<5120, 256, 0, stream>>>(x, x_bf, 2048 * 2560 / 4);
  tcast<<<dim3(128, 80), dim3(32, 8), 0, stream>>>(wq, wqkvT, 2560, 4096, 2560, 0);
  tcast<<<dim3(32, 80), dim3(32, 8), 0, stream>>>(wk, wqkvT, 2560, 1024, 2560, 4096);
  tcast<<<dim3(32, 80), dim3(32, 8), 0, stream>>>(wv, wqkvT, 2560, 1024, 2560, 5120);
  tcast<<<dim3(80, 128), dim3(32, 8), 0, stream>>>(wo, woT, 4096, 2560, 4096, 0);
  gemm_bt<<<16 * 48, 256, 0, stream>>>(x_bf, wqkvT, qkv, 2048, 6144, 2560);
  normrope<<<2048 * 48, 128, 0, stream>>>(qkv, positions, qnw, knw, q_bf, k_bf, vt_bf);
  attn<<<dim3(8, 32, 2), 256, 0, stream>>>(q_bf, k_bf, vt_bf, a_bf);
  gemm_bt<<<16 * 20, 256, 0, stream>>>(a_bf, woT, out, 2048, 2560, 4096);
}

// Round 4
// 307.566 us; speedup vs baseline: 1.3191x; 1.2381x over previous
//
#include <hip/hip_runtime.h>
#include <hip/hip_bf16.h>

typedef __attribute__((ext_vector_type(8))) __bf16 bf8_t;
typedef __attribute__((ext_vector_type(4))) float f32x4;

#define GLOAD16(gptr, lptr)                                                              \
  __builtin_amdgcn_global_load_lds((const __attribute__((address_space(1))) void*)(gptr), \
                                   (__attribute__((address_space(3))) void*)(lptr), 16, 0, 0)

__device__ __forceinline__ unsigned short f2bf(float f) {
  union { float f; unsigned u; } v; v.f = f;
  return (unsigned short)((v.u + 0x7fffu + ((v.u >> 16) & 1u)) >> 16);
}

// ---------- cast f32 -> bf16 ----------
__global__ void cast_bf16(const float* __restrict__ in, unsigned short* __restrict__ out, int n4) {
  int i = blockIdx.x * blockDim.x + threadIdx.x;
  if (i >= n4) return;
  float4 v = ((const float4*)in)[i];
  ushort4 o;
  o.x = f2bf(v.x); o.y = f2bf(v.y); o.z = f2bf(v.z); o.w = f2bf(v.w);
  ((ushort4*)out)[i] = o;
}

// ---------- transpose-cast ----------
__global__ void tcast(const float* __restrict__ in, unsigned short* __restrict__ out,
                      int R, int C, int ld, int rowOff) {
  __shared__ float tile[32][33];
  int c0 = blockIdx.x * 32, r0 = blockIdx.y * 32;
  int tx = threadIdx.x, ty = threadIdx.y;
#pragma unroll
  for (int i = 0; i < 4; ++i)
    tile[ty + 8 * i][tx] = in[(size_t)(r0 + ty + 8 * i) * C + c0 + tx];
  __syncthreads();
#pragma unroll
  for (int i = 0; i < 4; ++i)
    out[(size_t)(rowOff + c0 + ty + 8 * i) * ld + r0 + tx] = f2bf(tile[tx][ty + 8 * i]);
}

// ---------- 256x256-tile bf16 GEMM, BK=32, 4-buffer counted-vmcnt pipeline ----------
// C[M][N] = A[M][ldk] (bf16) * Bt[N][ldk]^T, f32 out. Optional split-K via blockIdx.y.
__global__ __launch_bounds__(512, 2) void gemm256(
    const unsigned short* __restrict__ A,
    const unsigned short* __restrict__ Bt,
    float* __restrict__ C0, float* __restrict__ C1,
    int N, int ldk, int Kslice, int nTileN) {
  __shared__ unsigned short SM[4][2][8192];  // [buf][A|B][256 rows x 32 cols]
  int ks = blockIdx.y;
  float* __restrict__ C = ks ? C1 : C0;
  int kbase = ks * Kslice;
  int bm = blockIdx.x / nTileN, bn = blockIdx.x % nTileN;
  int m0 = bm << 8, n0 = bn << 8;
  int tid = threadIdx.x, lane = tid & 63, w = tid >> 6;
  int wm = w >> 2, wn = w & 3;          // 2 x 4 wave grid; wave tile 128x64
  int lrow = lane & 15, lch = lane >> 4;
  int srow = tid >> 2, scol = (tid & 3) << 3;
  int nt = Kslice >> 5;

  f32x4 acc[8][4] = {};

  auto stage = [&](int t) {
    int buf = t & 3;
    int k0 = kbase + (t << 5);
    const unsigned short* Ag = A + (size_t)(m0 + srow) * ldk + k0 + scol;
    const unsigned short* Bg = Bt + (size_t)(n0 + srow) * ldk + k0 + scol;
    unsigned short* Al = &SM[buf][0][w << 9];
    unsigned short* Bl = &SM[buf][1][w << 9];
    GLOAD16(Ag, Al);
    GLOAD16(Ag + (size_t)128 * ldk, Al + 4096);
    GLOAD16(Bg, Bl);
    GLOAD16(Bg + (size_t)128 * ldk, Bl + 4096);
  };

  stage(0);
  stage(1);
  for (int t = 0; t < nt; ++t) {
    if (t + 2 < nt) stage(t + 2);
    // counted vmcnt: tile t guaranteed landed; up to 8 loads (tiles t+1,t+2) stay in flight
    if (t + 2 < nt)      asm volatile("s_waitcnt vmcnt(8)" ::: "memory");
    else if (t + 1 < nt) asm volatile("s_waitcnt vmcnt(4)" ::: "memory");
    else                 asm volatile("s_waitcnt vmcnt(0)" ::: "memory");
    asm volatile("s_barrier" ::: "memory");  // raw barrier: no vmcnt(0) drain
    int buf = t & 3;
    const unsigned short* As = &SM[buf][0][0];
    const unsigned short* Bs = &SM[buf][1][0];
    bf8_t a[8], b[4];
#pragma unroll
    for (int mi = 0; mi < 8; ++mi)
      a[mi] = *(const bf8_t*)(As + ((wm << 7) + (mi << 4) + lrow) * 32 + (lch << 3));
#pragma unroll
    for (int ni = 0; ni < 4; ++ni)
      b[ni] = *(const bf8_t*)(Bs + ((wn << 6) + (ni << 4) + lrow) * 32 + (lch << 3));
    __builtin_amdgcn_s_setprio(1);
#pragma unroll
    for (int mi = 0; mi < 8; ++mi)
#pragma unroll
      for (int ni = 0; ni < 4; ++ni)
        acc[mi][ni] = __builtin_amdgcn_mfma_f32_16x16x32_bf16(a[mi], b[ni], acc[mi][ni], 0, 0, 0);
    __builtin_amdgcn_s_setprio(0);
  }
  int r0 = m0 + (wm << 7) + (lch << 2);
  int c0 = n0 + (wn << 6) + lrow;
#pragma unroll
  for (int mi = 0; mi < 8; ++mi)
#pragma unroll
    for (int ni = 0; ni < 4; ++ni)
#pragma unroll
      for (int r = 0; r < 4; ++r)
        C[(size_t)(r0 + (mi << 4) + r) * N + c0 + (ni << 4)] = acc[mi][ni][r];
}

// ---------- split-K reduce ----------
__global__ void reduce_add(const float4* __restrict__ a, const float4* __restrict__ b,
                           float4* __restrict__ o, int n4) {
  int i = blockIdx.x * blockDim.x + threadIdx.x;
  if (i >= n4) return;
  float4 x = a[i], y = b[i];
  o[i] = make_float4(x.x + y.x, x.y + y.y, x.z + y.z, x.w + y.w);
}

// ---------- fused RMS-norm + RoPE + layout shuffle ----------
__global__ __launch_bounds__(128) void normrope(
    const float* __restrict__ qkv, const int* __restrict__ positions,
    const float* __restrict__ qw, const float* __restrict__ kw,
    unsigned short* __restrict__ qb, unsigned short* __restrict__ kb,
    unsigned short* __restrict__ vt) {
  int blk = blockIdx.x;
  int hh = blk % 48, bt = blk / 48;
  int b = bt >> 10, t = bt & 1023;
  int tid = threadIdx.x;
  int colbase = (hh < 32) ? (hh << 7) : ((hh < 40) ? (4096 + ((hh - 32) << 7)) : (5120 + ((hh - 40) << 7)));
  float val = qkv[(size_t)bt * 6144 + colbase + tid];
  if (hh >= 40) {
    vt[((size_t)((b * 8 + hh - 40) * 128 + tid)) * 1024 + t] = f2bf(val);
    return;
  }
  __shared__ float red[2];
  __shared__ float xs[128];
  float ss = val * val;
#pragma unroll
  for (int m = 32; m >= 1; m >>= 1) ss += __shfl_xor(ss, m);
  if ((tid & 63) == 0) red[tid >> 6] = ss;
  __syncthreads();
  float rinv = rsqrtf((red[0] + red[1]) * (1.0f / 128.0f) + 1e-6f);
  float wgt = (hh < 32) ? qw[tid] : kw[tid];
  float xn = val * rinv * wgt;
  xs[tid] = xn;
  __syncthreads();
  float other = xs[tid ^ 64];
  int pos = positions[b * 1024 + t];
  int j = tid & 63;
  float ang = (float)pos * exp2f(-(float)j * 0.31143075889569027f);
  float sv = sinf(ang), cv = cosf(ang);
  float outv = (tid < 64) ? (xn * cv - other * sv) : (xn * cv + other * sv);
  unsigned short o = f2bf(outv);
  if (hh < 32) qb[((size_t)((b * 32 + hh) * 1024 + t)) * 128 + tid] = o;
  else kb[((size_t)((b * 8 + hh - 32) * 1024 + t)) * 128 + tid] = o;
}

// ---------- flash attention: paired Q-tiles, dbuf gload staging, swizzled LDS ----------
__global__ __launch_bounds__(256) void attn(
    const unsigned short* __restrict__ qb,
    const unsigned short* __restrict__ kb,
    const unsigned short* __restrict__ vt,
    unsigned short* __restrict__ ob) {
  __shared__ unsigned short Ks[2][64 * 128];
  __shared__ unsigned short Vs[2][128 * 64];
  __shared__ unsigned short Ps[4][16 * 72];
  int qpair = blockIdx.x, hq = blockIdx.y, b = blockIdx.z;
  int qtA = qpair, qtB = 15 - qpair;
  int kvh = hq >> 2;
  int tid = threadIdx.x, lane = tid & 63, w = tid >> 6;
  int lrow = lane & 15, lko = (lane >> 4) << 3;
  const float scale = 0.08838834764831845f;

  const unsigned short* kbase = kb + ((size_t)(b * 8 + kvh) << 17);
  const unsigned short* vbase = vt + ((size_t)(b * 8 + kvh) << 17);

  int qArow = (qtA << 6) + (w << 4) + lrow;
  int qBrow = (qtB << 6) + (w << 4) + lrow;
  const unsigned short* qpA = qb + ((size_t)((b * 32 + hq) * 1024 + qArow) << 7);
  const unsigned short* qpB = qb + ((size_t)((b * 32 + hq) * 1024 + qBrow) << 7);
  bf8_t qaA[4], qaB[4];
#pragma unroll
  for (int kk = 0; kk < 4; ++kk) {
    qaA[kk] = *(const bf8_t*)(qpA + kk * 32 + lko);
    qaB[kk] = *(const bf8_t*)(qpB + kk * 32 + lko);
  }
  f32x4 accA[8] = {}, accB[8] = {};
  float mA[4], lA[4], mB[4], lB[4];
#pragma unroll
  for (int r = 0; r < 4; ++r) { mA[r] = mB[r] = -3.0e38f; lA[r] = lB[r] = 0.f; }

  int kr_l = lane >> 4, kc_l = lane & 15;
  int vr_l = lane >> 3, vc_l = lane & 7;

  auto stage = [&](int st, int buf) {
    int s0 = st << 6;
    unsigned short* kd = &Ks[buf][0];
    unsigned short* vd = &Vs[buf][0];
#pragma unroll
    for (int i = 0; i < 4; ++i) {
      int si = (w << 2) + i;
      int kr = (si << 2) + kr_l;
      GLOAD16(kbase + (size_t)(s0 + kr) * 128 + ((kc_l ^ (kr & 7)) << 3), kd + (si << 9));
      int vr = (si << 3) + vr_l;
      GLOAD16(vbase + (size_t)vr * 1024 + s0 + ((vc_l ^ (vr & 7)) << 3), vd + (si << 9));
    }
  };

  int qArow0 = (qtA << 6) + (w << 4) + ((lane >> 4) << 2);
  int qBrow0 = (qtB << 6) + (w << 4) + ((lane >> 4) << 2);
  unsigned short* psw = &Ps[w][0];

  auto tilec = [&](int buf, int s0, const bf8_t* qa, f32x4* accO, float* mrun, float* lrun,
                   int qrow0, bool domask) {
    const char* Kb = (const char*)&Ks[buf][0];
    const char* Vb = (const char*)&Vs[buf][0];
    f32x4 sacc[4] = {};
#pragma unroll
    for (int kk = 0; kk < 4; ++kk)
#pragma unroll
      for (int ni = 0; ni < 4; ++ni) {
        int kr = (ni << 4) + lrow;
        const bf8_t* kf = (const bf8_t*)(Kb + kr * 256 + ((((kk << 2) | (lko >> 3)) ^ (kr & 7)) << 4));
        sacc[ni] = __builtin_amdgcn_mfma_f32_16x16x32_bf16(qa[kk], *kf, sacc[ni], 0, 0, 0);
      }
    float p[4][4], rmax[4];
#pragma unroll
    for (int r = 0; r < 4; ++r) rmax[r] = -3.0e38f;
#pragma unroll
    for (int ni = 0; ni < 4; ++ni) {
      int sc = s0 + ni * 16 + lrow;
#pragma unroll
      for (int r = 0; r < 4; ++r) {
        float sv = sacc[ni][r] * scale;
        if (domask) sv = (sc <= qrow0 + r) ? sv : -3.0e38f;
        p[ni][r] = sv;
        rmax[r] = fmaxf(rmax[r], sv);
      }
    }
#pragma unroll
    for (int m = 1; m <= 8; m <<= 1)
#pragma unroll
      for (int r = 0; r < 4; ++r) rmax[r] = fmaxf(rmax[r], __shfl_xor(rmax[r], m));
    float alpha[4], rsum[4];
#pragma unroll
    for (int r = 0; r < 4; ++r) {
      float mn = fmaxf(mrun[r], rmax[r]);
      alpha[r] = __expf(mrun[r] - mn);
      mrun[r] = mn;
      rsum[r] = 0.f;
    }
#pragma unroll
    for (int ni = 0; ni < 4; ++ni)
#pragma unroll
      for (int r = 0; r < 4; ++r) {
        float e = __expf(p[ni][r] - mrun[r]);
        p[ni][r] = e;
        rsum[r] += e;
      }
#pragma unroll
    for (int m = 1; m <= 8; m <<= 1)
#pragma unroll
      for (int r = 0; r < 4; ++r) rsum[r] += __shfl_xor(rsum[r], m);
#pragma unroll
    for (int r = 0; r < 4; ++r) lrun[r] = lrun[r] * alpha[r] + rsum[r];
#pragma unroll
    for (int ni = 0; ni < 8; ++ni)
#pragma unroll
      for (int r = 0; r < 4; ++r) accO[ni][r] *= alpha[r];
#pragma unroll
    for (int ni = 0; ni < 4; ++ni)
#pragma unroll
      for (int r = 0; r < 4; ++r)
        psw[(((lane >> 4) << 2) + r) * 72 + ni * 16 + lrow] = f2bf(p[ni][r]);
    bf8_t pa0 = *(const bf8_t*)(psw + lrow * 72 + lko);
    bf8_t pa1 = *(const bf8_t*)(psw + lrow * 72 + 32 + lko);
#pragma unroll
    for (int ni = 0; ni < 8; ++ni) {
      int vr = (ni << 4) + lrow;
      const bf8_t* v0 = (const bf8_t*)(Vb + vr * 128 + (((lko >> 3) ^ (vr & 7)) << 4));
      const bf8_t* v1 = (const bf8_t*)(Vb + vr * 128 + (((4 | (lko >> 3)) ^ (vr & 7)) << 4));
      accO[ni] = __builtin_amdgcn_mfma_f32_16x16x32_bf16(pa0, *v0, accO[ni], 0, 0, 0);
      accO[ni] = __builtin_amdgcn_mfma_f32_16x16x32_bf16(pa1, *v1, accO[ni], 0, 0, 0);
    }
  };

  stage(0, 0);
  for (int st = 0; st <= qtB; ++st) {
    int buf = st & 1;
    __syncthreads();
    if (st < qtB) stage(st + 1, buf ^ 1);
    if (st <= qtA) tilec(buf, st << 6, qaA, accA, mA, lA, qArow0, st == qtA);
    tilec(buf, st << 6, qaB, accB, mB, lB, qBrow0, st == qtB);
  }

  size_t rowA = (size_t)(b * 1024) + (qtA << 6) + (w << 4) + ((lane >> 4) << 2);
  size_t rowB = (size_t)(b * 1024) + (qtB << 6) + (w << 4) + ((lane >> 4) << 2);
#pragma unroll
  for (int r = 0; r < 4; ++r) {
    float invA = 1.0f / lA[r], invB = 1.0f / lB[r];
#pragma unroll
    for (int ni = 0; ni < 8; ++ni) {
      ob[(rowA + r) * 4096 + hq * 128 + ni * 16 + lrow] = f2bf(accA[ni][r] * invA);
      ob[(rowB + r) * 4096 + hq * 128 + ni * 16 + lrow] = f2bf(accB[ni][r] * invB);
    }
  }
}

extern "C" void kernel_launch(void* const* d_in, const int* in_sizes, int n_in,
                              void* d_out, int out_size, void* d_ws, size_t ws_size,
                              hipStream_t stream) {
  const float* x = (const float*)d_in[0];
  const int* positions = (const int*)d_in[1];
  const float* wq = (const float*)d_in[3];
  const float* wk = (const float*)d_in[4];
  const float* wv = (const float*)d_in[5];
  const float* wo = (const float*)d_in[6];
  const float* qnw = (const float*)d_in[7];
  const float* knw = (const float*)d_in[8];
  float* out = (float*)d_out;

  char* ws = (char*)d_ws;
  unsigned short* x_bf  = (unsigned short*)(ws);              // 2048x2560 bf16
  unsigned short* wqkvT = (unsigned short*)(ws + 10485760);   // 6144x2560 bf16
  unsigned short* woT   = (unsigned short*)(ws + 41943040);   // 2560x4096 bf16
  float*          qkv   = (float*)(ws + 62914560);            // 2048x6144 f32 (dead after normrope)
  float*          p0    = (float*)(ws + 62914560);            // split-K partial 0 (reuses qkv)
  float*          p1    = (float*)(ws + 83886080);            // split-K partial 1
  unsigned short* q_bf  = (unsigned short*)(ws + 113246208);  // [2][32][1024][128]
  unsigned short* k_bf  = (unsigned short*)(ws + 130023424);  // [2][8][1024][128]
  unsigned short* vt_bf = (unsigned short*)(ws + 134217728);  // [2][8][128][1024]
  unsigned short* a_bf  = (unsigned short*)(ws + 138412032);  // 2048x4096 bf16

  cast_bf16<<<5120, 256, 0, stream>>>(x, x_bf, 2048 * 2560 / 4);
  tcast<<<dim3(128, 80), dim3(32, 8), 0, stream>>>(wq, wqkvT, 2560, 4096, 2560, 0);
  tcast<<<dim3(32, 80), dim3(32, 8), 0, stream>>>(wk, wqkvT, 2560, 1024, 2560, 4096);
  tcast<<<dim3(32, 80), dim3(32, 8), 0, stream>>>(wv, wqkvT, 2560, 1024, 2560, 5120);
  tcast<<<dim3(80, 128), dim3(32, 8), 0, stream>>>(wo, woT, 4096, 2560, 4096, 0);
  // QKV projection: 2048x6144x2560, single K-slice
  gemm256<<<dim3(8 * 24, 1), 512, 0, stream>>>(x_bf, wqkvT, qkv, nullptr, 6144, 2560, 2560, 24);
  normrope<<<2048 * 48, 128, 0, stream>>>(qkv, positions, qnw, knw, q_bf, k_bf, vt_bf);
  attn<<<dim3(8, 32, 2), 256, 0, stream>>>(q_bf, k_bf, vt_bf, a_bf);
  // out-projection: 2048x2560x4096, split-K=2 (qkv region is dead; reused for partials)
  gemm256<<<dim3(8 * 10, 2), 512, 0, stream>>>(a_bf, woT, p0, p1, 2560, 4096, 2048, 10);
  reduce_add<<<5120, 256, 0, stream>>>((const float4*)p0, (const float4*)p1, (float4*)out,
                                       2048 * 2560 / 4);
}

// Round 5
// 286.076 us; speedup vs baseline: 1.4182x; 1.0751x over previous
//
#include <hip/hip_runtime.h>
#include <hip/hip_bf16.h>

typedef __attribute__((ext_vector_type(8))) __bf16 bf8_t;
typedef __attribute__((ext_vector_type(4))) float f32x4;
typedef __attribute__((ext_vector_type(16))) float f32x16;

#define GLOAD16(gptr, lptr)                                                              \
  __builtin_amdgcn_global_load_lds((const __attribute__((address_space(1))) void*)(gptr), \
                                   (__attribute__((address_space(3))) void*)(lptr), 16, 0, 0)

__device__ __forceinline__ unsigned short f2bf(float f) {
  union { float f; unsigned u; } v; v.f = f;
  return (unsigned short)((v.u + 0x7fffu + ((v.u >> 16) & 1u)) >> 16);
}

__device__ __forceinline__ unsigned cvtpk_bf16(float a, float b) {
  unsigned r;
  asm("v_cvt_pk_bf16_f32 %0, %1, %2" : "=v"(r) : "v"(a), "v"(b));
  return r;
}

// ---------- cast f32 -> bf16 ----------
__global__ void cast_bf16(const float* __restrict__ in, unsigned short* __restrict__ out, int n4) {
  int i = blockIdx.x * blockDim.x + threadIdx.x;
  if (i >= n4) return;
  float4 v = ((const float4*)in)[i];
  ushort4 o;
  o.x = f2bf(v.x); o.y = f2bf(v.y); o.z = f2bf(v.z); o.w = f2bf(v.w);
  ((ushort4*)out)[i] = o;
}

// ---------- transpose-cast ----------
__global__ void tcast(const float* __restrict__ in, unsigned short* __restrict__ out,
                      int R, int C, int ld, int rowOff) {
  __shared__ float tile[32][33];
  int c0 = blockIdx.x * 32, r0 = blockIdx.y * 32;
  int tx = threadIdx.x, ty = threadIdx.y;
#pragma unroll
  for (int i = 0; i < 4; ++i)
    tile[ty + 8 * i][tx] = in[(size_t)(r0 + ty + 8 * i) * C + c0 + tx];
  __syncthreads();
#pragma unroll
  for (int i = 0; i < 4; ++i)
    out[(size_t)(rowOff + c0 + ty + 8 * i) * ld + r0 + tx] = f2bf(tile[tx][ty + 8 * i]);
}

// ---------- 256x256-tile bf16 GEMM, BK=32, 4-buffer counted-vmcnt pipeline ----------
__global__ __launch_bounds__(512, 2) void gemm256(
    const unsigned short* __restrict__ A,
    const unsigned short* __restrict__ Bt,
    float* __restrict__ C0, float* __restrict__ C1,
    int N, int ldk, int Kslice, int nTileN) {
  __shared__ unsigned short SM[4][2][8192];
  int ks = blockIdx.y;
  float* __restrict__ C = ks ? C1 : C0;
  int kbase = ks * Kslice;
  int bm = blockIdx.x / nTileN, bn = blockIdx.x % nTileN;
  int m0 = bm << 8, n0 = bn << 8;
  int tid = threadIdx.x, lane = tid & 63, w = tid >> 6;
  int wm = w >> 2, wn = w & 3;
  int lrow = lane & 15, lch = lane >> 4;
  int srow = tid >> 2, scol = (tid & 3) << 3;
  int nt = Kslice >> 5;

  f32x4 acc[8][4] = {};

  auto stage = [&](int t) {
    int buf = t & 3;
    int k0 = kbase + (t << 5);
    const unsigned short* Ag = A + (size_t)(m0 + srow) * ldk + k0 + scol;
    const unsigned short* Bg = Bt + (size_t)(n0 + srow) * ldk + k0 + scol;
    unsigned short* Al = &SM[buf][0][w << 9];
    unsigned short* Bl = &SM[buf][1][w << 9];
    GLOAD16(Ag, Al);
    GLOAD16(Ag + (size_t)128 * ldk, Al + 4096);
    GLOAD16(Bg, Bl);
    GLOAD16(Bg + (size_t)128 * ldk, Bl + 4096);
  };

  stage(0);
  stage(1);
  for (int t = 0; t < nt; ++t) {
    if (t + 2 < nt) stage(t + 2);
    if (t + 2 < nt)      asm volatile("s_waitcnt vmcnt(8)" ::: "memory");
    else if (t + 1 < nt) asm volatile("s_waitcnt vmcnt(4)" ::: "memory");
    else                 asm volatile("s_waitcnt vmcnt(0)" ::: "memory");
    asm volatile("s_barrier" ::: "memory");
    int buf = t & 3;
    const unsigned short* As = &SM[buf][0][0];
    const unsigned short* Bs = &SM[buf][1][0];
    bf8_t a[8], b[4];
#pragma unroll
    for (int mi = 0; mi < 8; ++mi)
      a[mi] = *(const bf8_t*)(As + ((wm << 7) + (mi << 4) + lrow) * 32 + (lch << 3));
#pragma unroll
    for (int ni = 0; ni < 4; ++ni)
      b[ni] = *(const bf8_t*)(Bs + ((wn << 6) + (ni << 4) + lrow) * 32 + (lch << 3));
    __builtin_amdgcn_s_setprio(1);
#pragma unroll
    for (int mi = 0; mi < 8; ++mi)
#pragma unroll
      for (int ni = 0; ni < 4; ++ni)
        acc[mi][ni] = __builtin_amdgcn_mfma_f32_16x16x32_bf16(a[mi], b[ni], acc[mi][ni], 0, 0, 0);
    __builtin_amdgcn_s_setprio(0);
  }
  int r0 = m0 + (wm << 7) + (lch << 2);
  int c0 = n0 + (wn << 6) + lrow;
#pragma unroll
  for (int mi = 0; mi < 8; ++mi)
#pragma unroll
    for (int ni = 0; ni < 4; ++ni)
#pragma unroll
      for (int r = 0; r < 4; ++r)
        C[(size_t)(r0 + (mi << 4) + r) * N + c0 + (ni << 4)] = acc[mi][ni][r];
}

// ---------- split-K reduce ----------
__global__ void reduce_add(const float4* __restrict__ a, const float4* __restrict__ b,
                           float4* __restrict__ o, int n4) {
  int i = blockIdx.x * blockDim.x + threadIdx.x;
  if (i >= n4) return;
  float4 x = a[i], y = b[i];
  o[i] = make_float4(x.x + y.x, x.y + y.y, x.z + y.z, x.w + y.w);
}

// ---------- fused RMS-norm + RoPE + layout shuffle ----------
__global__ __launch_bounds__(128) void normrope(
    const float* __restrict__ qkv, const int* __restrict__ positions,
    const float* __restrict__ qw, const float* __restrict__ kw,
    unsigned short* __restrict__ qb, unsigned short* __restrict__ kb,
    unsigned short* __restrict__ vt) {
  int blk = blockIdx.x;
  int hh = blk % 48, bt = blk / 48;
  int b = bt >> 10, t = bt & 1023;
  int tid = threadIdx.x;
  int colbase = (hh < 32) ? (hh << 7) : ((hh < 40) ? (4096 + ((hh - 32) << 7)) : (5120 + ((hh - 40) << 7)));
  float val = qkv[(size_t)bt * 6144 + colbase + tid];
  if (hh >= 40) {
    vt[((size_t)((b * 8 + hh - 40) * 128 + tid)) * 1024 + t] = f2bf(val);
    return;
  }
  __shared__ float red[2];
  __shared__ float xs[128];
  float ss = val * val;
#pragma unroll
  for (int m = 32; m >= 1; m >>= 1) ss += __shfl_xor(ss, m);
  if ((tid & 63) == 0) red[tid >> 6] = ss;
  __syncthreads();
  float rinv = rsqrtf((red[0] + red[1]) * (1.0f / 128.0f) + 1e-6f);
  float wgt = (hh < 32) ? qw[tid] : kw[tid];
  float xn = val * rinv * wgt;
  xs[tid] = xn;
  __syncthreads();
  float other = xs[tid ^ 64];
  int pos = positions[b * 1024 + t];
  int j = tid & 63;
  float ang = (float)pos * exp2f(-(float)j * 0.31143075889569027f);
  float sv = sinf(ang), cv = cosf(ang);
  float outv = (tid < 64) ? (xn * cv - other * sv) : (xn * cv + other * sv);
  unsigned short o = f2bf(outv);
  if (hh < 32) qb[((size_t)((b * 32 + hh) * 1024 + t)) * 128 + tid] = o;
  else kb[((size_t)((b * 8 + hh - 32) * 1024 + t)) * 128 + tid] = o;
}

// ---------- flash attention v3: swapped-operand 32x32 MFMA, in-register softmax ----------
// Per wave: 32 q-rows. Block: 4 waves = 128-row Q-tile. KVBLK=64, dbuf K/V in LDS.
// QK^T: S = mfma(K, Q)  -> S[k-regs][q-lanes]; softmax per-lane (q = lane&31).
// PV:   O = mfma(V^T, P) -> O[d-regs][q-lanes]; P repacked in-register (cvt_pk + shfl^32).
__global__ __launch_bounds__(256, 2) void attn(
    const unsigned short* __restrict__ qb,
    const unsigned short* __restrict__ kb,
    const unsigned short* __restrict__ vt,
    unsigned short* __restrict__ ob) {
  __shared__ unsigned short Kl[2][64 * 128];   // 16B-slot swizzle: slot ^ (row&15)
  __shared__ unsigned short Vl[2][128 * 64];   // V^T tile; slot ^ (row&7)
  int bx = blockIdx.x, hq = blockIdx.y, b = blockIdx.z;
  int qt = (bx < 4) ? (7 - bx) : (bx - 4);     // longest-first dispatch (LPT)
  int kvh = hq >> 2;
  int tid = threadIdx.x, lane = tid & 63, w = tid >> 6;
  int qlane = lane & 31, h = lane >> 5;
  int q0 = (qt << 7) + (w << 5);
  int qg = q0 + qlane;
  const unsigned short* kbase = kb + ((size_t)(b * 8 + kvh) << 17);
  const unsigned short* vbase = vt + ((size_t)(b * 8 + kvh) << 17);
  const float c2 = 0.12751744f;  // (1/sqrt(128)) * log2(e)

  // Q fragment (B-operand): qf[ds] = Q[qg][ds*16 + h*8 .. +8)
  const unsigned short* qptr = qb + ((size_t)((b * 32 + hq) * 1024 + qg) << 7) + (h << 3);
  bf8_t qf[8];
#pragma unroll
  for (int ds = 0; ds < 8; ++ds) qf[ds] = *(const bf8_t*)(qptr + ds * 16);

  f32x16 o[4] = {};            // o[db]: O[q=qlane][d = db*32 + (e&3)+8*(e>>2)+4h]
  float mrun = -3.0e38f, lrun = 0.f;
  int last_st = (q0 + 31) >> 6;
  int nsteps = 2 * qt + 2;

  auto stage = [&](int st, int buf) {
    int s0 = st << 6;
    unsigned short* kd = &Kl[buf][0];
    unsigned short* vd = &Vl[buf][0];
#pragma unroll
    for (int i = 0; i < 4; ++i) {
      int cid = i * 256 + tid;
      int kr = cid >> 4, ksl = cid & 15;
      GLOAD16(kbase + (size_t)(s0 + kr) * 128 + ((ksl ^ (kr & 15)) << 3), kd + cid * 8);
      int vr = cid >> 3, vsl = cid & 7;
      GLOAD16(vbase + (size_t)vr * 1024 + s0 + ((vsl ^ (vr & 7)) << 3), vd + cid * 8);
    }
  };

  stage(0, 0);
  for (int st = 0; st < nsteps; ++st) {
    __syncthreads();  // compiler drains vmcnt before s_barrier: staged tile ready
    if (st + 1 < nsteps) stage(st + 1, (st + 1) & 1);
    if (st <= last_st) {
      const char* Kb = (const char*)&Kl[st & 1][0];
      const char* Vb = (const char*)&Vl[st & 1][0];
      // ---- QK^T (swapped): S[k][q] ----
      f32x16 s0v = {}, s1v = {};
#pragma unroll
      for (int ds = 0; ds < 8; ++ds) {
        int c = ds * 2 + h;
        int r0 = qlane, r1 = 32 + qlane;
        bf8_t k0 = *(const bf8_t*)(Kb + r0 * 256 + ((c ^ (r0 & 15)) << 4));
        bf8_t k1 = *(const bf8_t*)(Kb + r1 * 256 + ((c ^ (r1 & 15)) << 4));
        s0v = __builtin_amdgcn_mfma_f32_32x32x16_bf16(k0, qf[ds], s0v, 0, 0, 0);
        s1v = __builtin_amdgcn_mfma_f32_32x32x16_bf16(k1, qf[ds], s1v, 0, 0, 0);
      }
      // ---- mask + row-max (in-lane + one lane^32 exchange) ----
      bool dm = (st == last_st);
      int kg0 = st << 6;
      float mt = -3.0e38f;
#pragma unroll
      for (int e = 0; e < 16; ++e) {
        int kl = (e & 3) + 8 * (e >> 2) + 4 * h;
        if (dm) {
          if (kg0 + kl > qg) s0v[e] = -3.0e38f;
          if (kg0 + 32 + kl > qg) s1v[e] = -3.0e38f;
        }
        mt = fmaxf(mt, fmaxf(s0v[e], s1v[e]));
      }
      mt = fmaxf(mt, __shfl_xor(mt, 32));
      float mnew = fmaxf(mrun, mt);
      float alpha = exp2f((mrun - mnew) * c2);
      // ---- exp + row-sum ----
      float ls = 0.f;
#pragma unroll
      for (int e = 0; e < 16; ++e) {
        s0v[e] = exp2f((s0v[e] - mnew) * c2);
        s1v[e] = exp2f((s1v[e] - mnew) * c2);
        ls += s0v[e] + s1v[e];
      }
      ls += __shfl_xor(ls, 32);
      lrun = lrun * alpha + ls;
      mrun = mnew;
#pragma unroll
      for (int db = 0; db < 4; ++db)
#pragma unroll
        for (int e = 0; e < 16; ++e) o[db][e] *= alpha;
      // ---- P repack to B-frags, fully in-register (cvt_pk + lane^32 exchange) ----
      bf8_t pf[4];
#pragma unroll
      for (int s = 0; s < 4; ++s) {
        // quad X0 = 2s, X1 = 2s+1: acc = X>>2, regbase = 4*(X&3)
        unsigned w00, w01, w10, w11;
        {
          const int B0 = 4 * ((2 * s) & 3);
          if ((2 * s) >> 2) { w00 = cvtpk_bf16(s1v[B0], s1v[B0 + 1]); w01 = cvtpk_bf16(s1v[B0 + 2], s1v[B0 + 3]); }
          else              { w00 = cvtpk_bf16(s0v[B0], s0v[B0 + 1]); w01 = cvtpk_bf16(s0v[B0 + 2], s0v[B0 + 3]); }
        }
        {
          const int B1 = 4 * ((2 * s + 1) & 3);
          if ((2 * s + 1) >> 2) { w10 = cvtpk_bf16(s1v[B1], s1v[B1 + 1]); w11 = cvtpk_bf16(s1v[B1 + 2], s1v[B1 + 3]); }
          else                  { w10 = cvtpk_bf16(s0v[B1], s0v[B1 + 1]); w11 = cvtpk_bf16(s0v[B1 + 2], s0v[B1 + 3]); }
        }
        unsigned sa = h ? w00 : w10, sb = h ? w01 : w11;   // send quad X(2s+1-h)
        unsigned ra = __shfl_xor(sa, 32), rb = __shfl_xor(sb, 32);
        unsigned ka = h ? w10 : w00, kb2 = h ? w11 : w01;  // keep quad X(2s+h)
        unsigned f0 = h ? ra : ka, f1 = h ? rb : kb2;
        unsigned f2 = h ? ka : ra, f3 = h ? kb2 : rb;
        uint4 fv = make_uint4(f0, f1, f2, f3);
        pf[s] = *(bf8_t*)&fv;
      }
      // ---- PV (swapped): O[d][q] += V^T-frag x P-frag ----
#pragma unroll
      for (int db = 0; db < 4; ++db) {
        int vr = (db << 5) + qlane;
#pragma unroll
        for (int s = 0; s < 4; ++s) {
          int c = (s << 1) + h;
          bf8_t vf = *(const bf8_t*)(Vb + vr * 128 + ((c ^ (vr & 7)) << 4));
          o[db] = __builtin_amdgcn_mfma_f32_32x32x16_bf16(vf, pf[s], o[db], 0, 0, 0);
        }
      }
    }
  }

  // ---- epilogue: normalize, transpose via LDS, coalesced bf16 store ----
  __syncthreads();
  unsigned short* tb = &Kl[0][0] + (w << 12);  // 4096 shorts per wave
  float inv = 1.0f / lrun;
#pragma unroll
  for (int db = 0; db < 4; ++db)
#pragma unroll
    for (int rq = 0; rq < 4; ++rq) {
      int d0 = (db << 5) + (rq << 3) + (h << 2);
      unsigned lo = ((unsigned)f2bf(o[db][rq * 4 + 1] * inv) << 16) | f2bf(o[db][rq * 4 + 0] * inv);
      unsigned hi = ((unsigned)f2bf(o[db][rq * 4 + 3] * inv) << 16) | f2bf(o[db][rq * 4 + 2] * inv);
      *(uint2*)(tb + qlane * 128 + (d0 ^ ((qlane & 15) << 3))) = make_uint2(lo, hi);
    }
  int rr = lane >> 1, dh = (lane & 1) << 6;
  size_t orow = ((size_t)(b * 1024 + q0 + rr) << 12) + (hq << 7);
#pragma unroll
  for (int i = 0; i < 8; ++i) {
    int d8 = dh + i * 8;
    uint4 vv = *(const uint4*)(tb + rr * 128 + (d8 ^ ((rr & 15) << 3)));
    *(uint4*)(&ob[orow + d8]) = vv;
  }
}

extern "C" void kernel_launch(void* const* d_in, const int* in_sizes, int n_in,
                              void* d_out, int out_size, void* d_ws, size_t ws_size,
                              hipStream_t stream) {
  const float* x = (const float*)d_in[0];
  const int* positions = (const int*)d_in[1];
  const float* wq = (const float*)d_in[3];
  const float* wk = (const float*)d_in[4];
  const float* wv = (const float*)d_in[5];
  const float* wo = (const float*)d_in[6];
  const float* qnw = (const float*)d_in[7];
  const float* knw = (const float*)d_in[8];
  float* out = (float*)d_out;

  char* ws = (char*)d_ws;
  unsigned short* x_bf  = (unsigned short*)(ws);              // 2048x2560 bf16
  unsigned short* wqkvT = (unsigned short*)(ws + 10485760);   // 6144x2560 bf16
  unsigned short* woT   = (unsigned short*)(ws + 41943040);   // 2560x4096 bf16
  float*          qkv   = (float*)(ws + 62914560);            // 2048x6144 f32 (dead after normrope)
  float*          p0    = (float*)(ws + 62914560);            // split-K partial 0 (reuses qkv)
  float*          p1    = (float*)(ws + 83886080);            // split-K partial 1
  unsigned short* q_bf  = (unsigned short*)(ws + 113246208);  // [2][32][1024][128]
  unsigned short* k_bf  = (unsigned short*)(ws + 130023424);  // [2][8][1024][128]
  unsigned short* vt_bf = (unsigned short*)(ws + 134217728);  // [2][8][128][1024]
  unsigned short* a_bf  = (unsigned short*)(ws + 138412032);  // 2048x4096 bf16

  cast_bf16<<<5120, 256, 0, stream>>>(x, x_bf, 2048 * 2560 / 4);
  tcast<<<dim3(128, 80), dim3(32, 8), 0, stream>>>(wq, wqkvT, 2560, 4096, 2560, 0);
  tcast<<<dim3(32, 80), dim3(32, 8), 0, stream>>>(wk, wqkvT, 2560, 1024, 2560, 4096);
  tcast<<<dim3(32, 80), dim3(32, 8), 0, stream>>>(wv, wqkvT, 2560, 1024, 2560, 5120);
  tcast<<<dim3(80, 128), dim3(32, 8), 0, stream>>>(wo, woT, 4096, 2560, 4096, 0);
  gemm256<<<dim3(8 * 24, 1), 512, 0, stream>>>(x_bf, wqkvT, qkv, nullptr, 6144, 2560, 2560, 24);
  normrope<<<2048 * 48, 128, 0, stream>>>(qkv, positions, qnw, knw, q_bf, k_bf, vt_bf);
  attn<<<dim3(8, 32, 2), 256, 0, stream>>>(q_bf, k_bf, vt_bf, a_bf);
  gemm256<<<dim3(8 * 10, 2), 512, 0, stream>>>(a_bf, woT, p0, p1, 2560, 4096, 2048, 10);
  reduce_add<<<5120, 256, 0, stream>>>((const float4*)p0, (const float4*)p1, (float4*)out,
                                       2048 * 2560 / 4);
}